// Round 2
// baseline (710.613 us; speedup 1.0000x reference)
//
#include <hip/hip_runtime.h>

typedef _Float16 half_t;
typedef _Float16 f16x8 __attribute__((ext_vector_type(8)));
typedef _Float16 f16x4 __attribute__((ext_vector_type(4)));
typedef float f32x4 __attribute__((ext_vector_type(4)));
typedef unsigned long long u64;

#define NN 6144
#define IN_DIM 512
#define DD 256
#define OUT_DIM 128
#define SPLIT 3
#define JTILES 32   // j-tiles of 64 per slice (2048/64)

__device__ __forceinline__ f32x4 mfma16(f16x8 a, f16x8 b, f32x4 c) {
  return __builtin_amdgcn_mfma_f32_16x16x32_f16(a, b, c, 0, 0, 0);
}

// ---------------- convert x (f32 -> f16) ----------------
__global__ void cvt_x_kernel(const float* __restrict__ x, half_t* __restrict__ xh) {
  int idx = (blockIdx.x * 256 + threadIdx.x) * 4;
  float4 v = *(const float4*)(x + idx);
  f16x4 h;
  h[0] = (half_t)v.x; h[1] = (half_t)v.y; h[2] = (half_t)v.z; h[3] = (half_t)v.w;
  *(f16x4*)(xh + idx) = h;
}

// ---------------- convert + transpose weights ----------------
__global__ void cvt_w_kernel(const float* __restrict__ W0, const float* __restrict__ W1,
                             const float* __restrict__ W2, const float* __restrict__ pW,
                             half_t* __restrict__ WT, half_t* __restrict__ pWT) {
  int y = blockIdx.y;
  int idx = blockIdx.x * 256 + threadIdx.x;
  if (y < 3) {
    const float* W = (y == 0) ? W0 : (y == 1) ? W1 : W2;
    int k = idx >> 8, n = idx & 255;
    WT[(size_t)y * DD * IN_DIM + (size_t)n * IN_DIM + k] = (half_t)W[idx];
  } else if (idx < DD * OUT_DIM) {
    int k = idx >> 7, o = idx & 127;
    pWT[(size_t)o * DD + k] = (half_t)pW[idx];
  }
}

// ---------------- adj pack: int32 -> bitmask ----------------
// layout: packed[v][row][seg*4 + c] (u64), seg = j>>8, c = j&3, bit = (j&255)>>2
__global__ __launch_bounds__(256) void pack_kernel(const int* __restrict__ a0,
    const int* __restrict__ a1, const int* __restrict__ a2, u64* __restrict__ packed) {
  int row = blockIdx.x, v = blockIdx.y;
  const int* __restrict__ adj = (v == 0) ? a0 : (v == 1) ? a1 : a2;
  int t = threadIdx.x, lane = t & 63, w = t >> 6;
  const int* arow = adj + (size_t)row * NN;
  u64* prow = packed + ((size_t)v * NN + row) * 96;
  for (int s = w; s < 24; s += 4) {
    int4 a = *(const int4*)(arow + s * 256 + lane * 4);
    u64 b0 = __ballot(a.x > 0);
    u64 b1 = __ballot(a.y > 0);
    u64 b2 = __ballot(a.z > 0);
    u64 b3 = __ballot(a.w > 0);
    if (lane == 0) {
      prow[s * 4 + 0] = b0; prow[s * 4 + 1] = b1;
      prow[s * 4 + 2] = b2; prow[s * 4 + 3] = b3;
    }
  }
}

// ---------------- GEMM1: hT[v][d][i] = (x @ W_v)^T in f16 ----------------
__global__ __launch_bounds__(256, 2) void gemm1_kernel(
    const half_t* __restrict__ xh, const half_t* __restrict__ WT,
    half_t* __restrict__ hT) {
  int v = blockIdx.y;
  int i0 = blockIdx.x * 64;
  int t = threadIdx.x;
  int lane = t & 63, w = t >> 6;
  int lr = lane & 15, lg = lane >> 4;
  const half_t* Wv = WT + (size_t)v * DD * IN_DIM;
  f32x4 acc[4][4] = {};
  for (int kt = 0; kt < 16; ++kt) {
    int k = kt * 32 + lg * 8;
    f16x8 af[4], bf[4];
#pragma unroll
    for (int mf = 0; mf < 4; ++mf)
      af[mf] = *(const f16x8*)(xh + (size_t)(i0 + mf * 16 + lr) * IN_DIM + k);
#pragma unroll
    for (int nf = 0; nf < 4; ++nf)
      bf[nf] = *(const f16x8*)(Wv + (size_t)(w * 64 + nf * 16 + lr) * IN_DIM + k);
#pragma unroll
    for (int mf = 0; mf < 4; ++mf)
#pragma unroll
      for (int nf = 0; nf < 4; ++nf)
        acc[mf][nf] = mfma16(af[mf], bf[nf], acc[mf][nf]);
  }
  __shared__ half_t tr[4][64 * 64];
  char* trw = (char*)tr[w];
#pragma unroll
  for (int mf = 0; mf < 4; ++mf)
#pragma unroll
    for (int nf = 0; nf < 4; ++nf)
#pragma unroll
      for (int r = 0; r < 4; ++r) {
        int dl = nf * 16 + lr;
        int il = mf * 16 + lg * 4 + r;
        unsigned addr = (unsigned)((dl * 128 + il * 2) ^ ((dl & 7) << 4));
        *(half_t*)(trw + addr) = (half_t)acc[mf][nf][r];
      }
  __syncthreads();
  half_t* hTv = hT + (size_t)v * DD * NN;
#pragma unroll
  for (int c = 0; c < 8; ++c) {
    unsigned addr = (unsigned)((lane * 128 + c * 16) ^ ((lane & 7) << 4));
    f16x8 val = *(const f16x8*)(trw + addr);
    *(f16x8*)(hTv + (size_t)(w * 64 + lane) * NN + i0 + c * 8) = val;
  }
}

// ---------------- e1/e2 scores ----------------
__global__ void escore_kernel(const half_t* __restrict__ hT,
    const float* __restrict__ as0, const float* __restrict__ as1, const float* __restrict__ as2,
    const float* __restrict__ ad0, const float* __restrict__ ad1, const float* __restrict__ ad2,
    float* __restrict__ e1, float* __restrict__ e2) {
  int v = blockIdx.y;
  int i = blockIdx.x * 256 + threadIdx.x;
  const float* as = (v == 0) ? as0 : (v == 1) ? as1 : as2;
  const float* ad = (v == 0) ? ad0 : (v == 1) ? ad1 : ad2;
  const half_t* h = hT + (size_t)v * DD * NN;
  float acc1 = 0.f, acc2 = 0.f;
  for (int d = 0; d < DD; ++d) {
    float hv = (float)h[(size_t)d * NN + i];
    acc1 = fmaf(hv, as[d], acc1);
    acc2 = fmaf(hv, ad[d], acc2);
  }
  e1[v * NN + i] = acc1;
  e2[v * NN + i] = acc2;
}

// ---------------- e2 max per view ----------------
__global__ void e2max_kernel(const float* __restrict__ e2, float* __restrict__ e2m) {
  int v = blockIdx.x;
  __shared__ float red[256];
  float m = -1e30f;
  for (int i = threadIdx.x; i < NN; i += 256) m = fmaxf(m, e2[v * NN + i]);
  red[threadIdx.x] = m;
  __syncthreads();
  for (int s = 128; s > 0; s >>= 1) {
    if (threadIdx.x < s) red[threadIdx.x] = fmaxf(red[threadIdx.x], red[threadIdx.x + s]);
    __syncthreads();
  }
  if (threadIdx.x == 0) e2m[v] = red[0];
}

// ---------------- fused GAT aggregation (packed adj, j-sliced) ----------------
// grid (96, SPLIT, 3): 64 rows x 2048 j's per block. Writes f16 partial acc + f32 partial l.
__global__ __launch_bounds__(256, 2) void gat_kernel(
    const u64* __restrict__ packed, const half_t* __restrict__ hT,
    const float* __restrict__ e1g, const float* __restrict__ e2g,
    const float* __restrict__ e2maxg, half_t* __restrict__ pacc, float* __restrict__ pl) {
  int v = blockIdx.z, s = blockIdx.y;
  int i0 = blockIdx.x * 64;
  int t = threadIdx.x;
  int lane = t & 63, w = t >> 6;
  int lr = lane & 15, lg = lane >> 4;
  int jq = t & 15;   // j-quad 0..15
  int rg = t >> 4;   // row group 0..15
  __shared__ half_t P_lds[64 * 64];
  __shared__ float e1_lds[64], m_lds[64], l_lds[64];
  if (t < 64) {
    float e1i = e1g[v * NN + i0 + t];
    e1_lds[t] = e1i;
    float mm = e1i + e2maxg[v];
    m_lds[t] = (mm > 0.f) ? mm : 0.2f * mm;  // lrelu upper bound of row max
  }
  const half_t* hTv = hT + (size_t)v * DD * NN;
  const float* e2v = e2g + v * NN;
  const int jt0 = s * JTILES;
  const u64* prow[4];
#pragma unroll
  for (int it = 0; it < 4; ++it)
    prow[it] = packed + ((size_t)v * NN + i0 + it * 16 + rg) * 96;
  f32x4 acc[4][4] = {};
  float lpart[4] = {0.f, 0.f, 0.f, 0.f};
  u64 aw[4][4];
  f16x8 bfr[2][2][4];
  // preload B tile 0 and packed seg 0
  {
    int j0 = jt0 * 64;
#pragma unroll
    for (int kf = 0; kf < 2; ++kf)
#pragma unroll
      for (int nf = 0; nf < 4; ++nf)
        bfr[0][kf][nf] = *(const f16x8*)(hTv + (size_t)(w * 64 + nf * 16 + lr) * NN +
                                         j0 + kf * 32 + lg * 8);
#pragma unroll
    for (int it = 0; it < 4; ++it) {
      ulonglong2 p01 = *(const ulonglong2*)(prow[it] + (jt0 >> 2) * 4);
      ulonglong2 p23 = *(const ulonglong2*)(prow[it] + (jt0 >> 2) * 4 + 2);
      aw[it][0] = p01.x; aw[it][1] = p01.y; aw[it][2] = p23.x; aw[it][3] = p23.y;
    }
  }
  __syncthreads();
  for (int jtt = 0; jtt < JTILES; ++jtt) {
    int jt = jt0 + jtt;
    int j0 = jt * 64;
    int cur = jtt & 1;
    float4 e2q = *(const float4*)(e2v + j0 + jq * 4);
    int bitidx = (jt & 3) * 16 + jq;
#pragma unroll
    for (int it = 0; it < 4; ++it) {
      int il = it * 16 + rg;
      float m = m_lds[il];
      float e1i = e1_lds[il];
      float e2a[4] = {e2q.x, e2q.y, e2q.z, e2q.w};
      f16x4 ph;
      float ssum = 0.f;
#pragma unroll
      for (int c = 0; c < 4; ++c) {
        float e = e1i + e2a[c];
        e = (e > 0.f) ? e : 0.2f * e;
        float p = ((aw[it][c] >> bitidx) & 1ull) ? __expf(e - m) : 0.f;
        ssum += p;
        ph[c] = (half_t)p;
      }
      lpart[it] += ssum;
      unsigned addr = (unsigned)((il * 128 + jq * 8) ^ ((il & 7) << 4));
      *(f16x4*)((char*)P_lds + addr) = ph;
    }
    // prefetch next B tile (and packed words at seg boundary) — hidden under MFMA
    if (jtt + 1 < JTILES) {
      int jn = j0 + 64;
#pragma unroll
      for (int kf = 0; kf < 2; ++kf)
#pragma unroll
        for (int nf = 0; nf < 4; ++nf)
          bfr[cur ^ 1][kf][nf] = *(const f16x8*)(hTv + (size_t)(w * 64 + nf * 16 + lr) * NN +
                                                 jn + kf * 32 + lg * 8);
      if (((jt + 1) & 3) == 0) {
#pragma unroll
        for (int it = 0; it < 4; ++it) {
          ulonglong2 p01 = *(const ulonglong2*)(prow[it] + ((jt + 1) >> 2) * 4);
          ulonglong2 p23 = *(const ulonglong2*)(prow[it] + ((jt + 1) >> 2) * 4 + 2);
          aw[it][0] = p01.x; aw[it][1] = p01.y; aw[it][2] = p23.x; aw[it][3] = p23.y;
        }
      }
    }
    __syncthreads();
#pragma unroll
    for (int kf = 0; kf < 2; ++kf)
#pragma unroll
      for (int mf = 0; mf < 4; ++mf) {
        int row = mf * 16 + lr;
        unsigned addr = (unsigned)((row * 128 + kf * 64 + lg * 16) ^ ((row & 7) << 4));
        f16x8 af = *(const f16x8*)((const char*)P_lds + addr);
#pragma unroll
        for (int nf = 0; nf < 4; ++nf)
          acc[mf][nf] = mfma16(af, bfr[cur][kf][nf], acc[mf][nf]);
      }
    __syncthreads();
  }
  // row partial sums
#pragma unroll
  for (int it = 0; it < 4; ++it) {
    float ssum = lpart[it];
    ssum += __shfl_xor(ssum, 1); ssum += __shfl_xor(ssum, 2);
    ssum += __shfl_xor(ssum, 4); ssum += __shfl_xor(ssum, 8);
    if (lr == 0) l_lds[it * 16 + rg] = ssum;
  }
  __syncthreads();
  size_t sl = (size_t)v * SPLIT + s;
  if (t < 64) pl[sl * NN + i0 + t] = l_lds[t];
  half_t* pa = pacc + sl * (size_t)NN * DD;
#pragma unroll
  for (int mf = 0; mf < 4; ++mf)
#pragma unroll
    for (int r = 0; r < 4; ++r) {
      int il = mf * 16 + lg * 4 + r;
#pragma unroll
      for (int nf = 0; nf < 4; ++nf)
        pa[(size_t)(i0 + il) * DD + w * 64 + nf * 16 + lr] = (half_t)acc[mf][nf][r];
    }
}

// ---------------- combine slices + normalize ----------------
__global__ __launch_bounds__(256) void combine_kernel(const half_t* __restrict__ pacc,
    const float* __restrict__ pl, half_t* __restrict__ outv) {
  int gid = blockIdx.x * 256 + threadIdx.x;  // 3*6144*32 threads
  int v = gid / (NN * 32);
  int rem = gid - v * (NN * 32);
  int i = rem >> 5, d0 = (rem & 31) * 8;
  float l = pl[((size_t)v * SPLIT + 0) * NN + i] +
            pl[((size_t)v * SPLIT + 1) * NN + i] +
            pl[((size_t)v * SPLIT + 2) * NN + i];
  float rl = (l > 0.f) ? 1.f / l : 0.f;
  f16x8 a0 = *(const f16x8*)(pacc + (((size_t)v * SPLIT + 0) * NN + i) * DD + d0);
  f16x8 a1 = *(const f16x8*)(pacc + (((size_t)v * SPLIT + 1) * NN + i) * DD + d0);
  f16x8 a2 = *(const f16x8*)(pacc + (((size_t)v * SPLIT + 2) * NN + i) * DD + d0);
  f16x8 o;
#pragma unroll
  for (int e = 0; e < 8; ++e)
    o[e] = (half_t)(((float)a0[e] + (float)a1[e] + (float)a2[e]) * rl);
  *(f16x8*)(outv + ((size_t)v * NN + i) * DD + d0) = o;
}

// ---------------- proj + LN + weighted combine ----------------
__global__ __launch_bounds__(256, 2) void proj_kernel(
    const half_t* __restrict__ outv, const half_t* __restrict__ pWT,
    const float* __restrict__ proj_b, const float* __restrict__ ln_g,
    const float* __restrict__ ln_b, const float* __restrict__ alpha,
    float* __restrict__ out) {
  int i0 = blockIdx.x * 64;
  int t = threadIdx.x, lane = t & 63, w = t >> 6;
  int lr = lane & 15, lg = lane >> 4;
  float a0 = alpha[0], a1 = alpha[1], a2 = alpha[2];
  float am = fmaxf(a0, fmaxf(a1, a2));
  float x0 = __expf(a0 - am), x1 = __expf(a1 - am), x2 = __expf(a2 - am);
  float inv = 1.f / (x0 + x1 + x2);
  float wv[3] = {x0 * inv, x1 * inv, x2 * inv};
  f32x4 zacc[8] = {};
  float pb[8], gg[8], bb[8];
#pragma unroll
  for (int nf = 0; nf < 8; ++nf) {
    pb[nf] = proj_b[nf * 16 + lr];
    gg[nf] = ln_g[nf * 16 + lr];
    bb[nf] = ln_b[nf * 16 + lr];
  }
  for (int v = 0; v < 3; ++v) {
    f32x4 yac[8] = {};
    const half_t* ovv = outv + (size_t)v * NN * DD;
    for (int kt = 0; kt < 8; ++kt) {
      int k = kt * 32 + lg * 8;
      f16x8 af = *(const f16x8*)(ovv + (size_t)(i0 + w * 16 + lr) * DD + k);
#pragma unroll
      for (int nf = 0; nf < 8; ++nf) {
        f16x8 bf = *(const f16x8*)(pWT + (size_t)(nf * 16 + lr) * DD + k);
        yac[nf] = mfma16(af, bf, yac[nf]);
      }
    }
#pragma unroll
    for (int r = 0; r < 4; ++r) {
      float ssum = 0.f, q = 0.f;
#pragma unroll
      for (int nf = 0; nf < 8; ++nf) {
        float y = yac[nf][r] + pb[nf];
        yac[nf][r] = y;
        ssum += y; q += y * y;
      }
      ssum += __shfl_xor(ssum, 1); ssum += __shfl_xor(ssum, 2);
      ssum += __shfl_xor(ssum, 4); ssum += __shfl_xor(ssum, 8);
      q += __shfl_xor(q, 1); q += __shfl_xor(q, 2);
      q += __shfl_xor(q, 4); q += __shfl_xor(q, 8);
      float mean = ssum * (1.f / 128.f);
      float var = q * (1.f / 128.f) - mean * mean;
      float rstd = rsqrtf(var + 1e-5f);
      float wvv = wv[v];
#pragma unroll
      for (int nf = 0; nf < 8; ++nf)
        zacc[nf][r] += wvv * (yac[nf][r] - mean) * rstd;
    }
  }
#pragma unroll
  for (int nf = 0; nf < 8; ++nf)
#pragma unroll
    for (int r = 0; r < 4; ++r) {
      int row = i0 + w * 16 + lg * 4 + r;
      float z = zacc[nf][r] * gg[nf] + bb[nf];
      if (!isfinite(z)) z = 0.f;
      out[(size_t)row * OUT_DIM + nf * 16 + lr] = z;
    }
  if (blockIdx.x == 0 && t < 3) out[(size_t)NN * OUT_DIM + t] = wv[t];
}

// ---------------- launch ----------------
extern "C" void kernel_launch(void* const* d_in, const int* in_sizes, int n_in,
                              void* d_out, int out_size, void* d_ws, size_t ws_size,
                              hipStream_t stream) {
  const float* x      = (const float*)d_in[0];
  const int*   adj_cf = (const int*)d_in[1];
  const int*   adj_or = (const int*)d_in[2];
  const int*   adj_pe = (const int*)d_in[3];
  const float* W_cf   = (const float*)d_in[4];
  const float* as_cf  = (const float*)d_in[5];
  const float* ad_cf  = (const float*)d_in[6];
  const float* W_or   = (const float*)d_in[7];
  const float* as_or  = (const float*)d_in[8];
  const float* ad_or  = (const float*)d_in[9];
  const float* W_pe   = (const float*)d_in[10];
  const float* as_pe  = (const float*)d_in[11];
  const float* ad_pe  = (const float*)d_in[12];
  const float* proj_W = (const float*)d_in[13];
  const float* proj_b = (const float*)d_in[14];
  const float* ln_g   = (const float*)d_in[15];
  const float* ln_b   = (const float*)d_in[16];
  const float* alpha  = (const float*)d_in[17];

  char* ws = (char*)d_ws;
  half_t* xh     = (half_t*)(ws + 0);         // 6291456
  half_t* WT     = (half_t*)(ws + 6291456);   // 786432
  half_t* pWT    = (half_t*)(ws + 7077888);   // 65536
  half_t* hT     = (half_t*)(ws + 7143424);   // 9437184
  float*  e1     = (float*)(ws + 16580608);   // 73728
  float*  e2     = (float*)(ws + 16654336);   // 73728
  float*  e2m    = (float*)(ws + 16728064);   // 64 (padded)
  half_t* outv   = (half_t*)(ws + 16728128);  // 9437184
  u64*    packed = (u64*)(ws + 26165312);     // 14155776
  half_t* pacc   = (half_t*)(ws + 40321088);  // 28311552
  float*  pl     = (float*)(ws + 68632640);   // 221184   (end ~68.85 MB)

  cvt_x_kernel<<<3072, 256, 0, stream>>>(x, xh);
  cvt_w_kernel<<<dim3(512, 4), 256, 0, stream>>>(W_cf, W_or, W_pe, proj_W, WT, pWT);
  gemm1_kernel<<<dim3(96, 3), 256, 0, stream>>>(xh, WT, hT);
  escore_kernel<<<dim3(24, 3), 256, 0, stream>>>(hT, as_cf, as_or, as_pe,
                                                 ad_cf, ad_or, ad_pe, e1, e2);
  e2max_kernel<<<3, 256, 0, stream>>>(e2, e2m);
  pack_kernel<<<dim3(6144, 3), 256, 0, stream>>>(adj_cf, adj_or, adj_pe, packed);
  gat_kernel<<<dim3(96, SPLIT, 3), 256, 0, stream>>>(packed, hT, e1, e2, e2m, pacc, pl);
  combine_kernel<<<2304, 256, 0, stream>>>(pacc, pl, outv);
  proj_kernel<<<96, 256, 0, stream>>>(outv, pWT, proj_b, ln_g, ln_b, alpha, (float*)d_out);
}

// Round 3
// 353.974 us; speedup vs baseline: 2.0075x; 2.0075x over previous
//
#include <hip/hip_runtime.h>

typedef _Float16 half_t;
typedef _Float16 f16x8 __attribute__((ext_vector_type(8)));
typedef _Float16 f16x4 __attribute__((ext_vector_type(4)));
typedef float f32x4 __attribute__((ext_vector_type(4)));
typedef unsigned long long u64;

#define NN 6144
#define IN_DIM 512
#define DD 256
#define OUT_DIM 128
#define SPLIT 3
#define JTILES 32   // j-tiles of 64 per slice (2048/64)
#define LOG2E 1.44269504088896340736f

__device__ __forceinline__ f32x4 mfma16(f16x8 a, f16x8 b, f32x4 c) {
  return __builtin_amdgcn_mfma_f32_16x16x32_f16(a, b, c, 0, 0, 0);
}

// ---------------- convert x (f32 -> f16) ----------------
__global__ void cvt_x_kernel(const float* __restrict__ x, half_t* __restrict__ xh) {
  int idx = (blockIdx.x * 256 + threadIdx.x) * 4;
  float4 v = *(const float4*)(x + idx);
  f16x4 h;
  h[0] = (half_t)v.x; h[1] = (half_t)v.y; h[2] = (half_t)v.z; h[3] = (half_t)v.w;
  *(f16x4*)(xh + idx) = h;
}

// ---------------- convert + transpose weights ----------------
__global__ void cvt_w_kernel(const float* __restrict__ W0, const float* __restrict__ W1,
                             const float* __restrict__ W2, const float* __restrict__ pW,
                             half_t* __restrict__ WT, half_t* __restrict__ pWT) {
  int y = blockIdx.y;
  int idx = blockIdx.x * 256 + threadIdx.x;
  if (y < 3) {
    const float* W = (y == 0) ? W0 : (y == 1) ? W1 : W2;
    int k = idx >> 8, n = idx & 255;
    WT[(size_t)y * DD * IN_DIM + (size_t)n * IN_DIM + k] = (half_t)W[idx];
  } else if (idx < DD * OUT_DIM) {
    int k = idx >> 7, o = idx & 127;
    pWT[(size_t)o * DD + k] = (half_t)pW[idx];
  }
}

// ---------------- adj pack: int32 -> bitmask, j-consecutive bits ----------------
// packed byte bp = row*768 + jb holds adj[row][jb*8 .. jb*8+8) ; as u64 word jt:
// bit b of word [row][jt] = adj[row][jt*64 + b]
__global__ __launch_bounds__(256) void pack_kernel(const int* __restrict__ a0,
    const int* __restrict__ a1, const int* __restrict__ a2,
    unsigned char* __restrict__ packed) {
  int v = blockIdx.y;
  const int* __restrict__ adj = (v == 0) ? a0 : (v == 1) ? a1 : a2;
  unsigned bp = blockIdx.x * 256 + threadIdx.x;   // byte position within view
  unsigned row = bp / 768u, jb = bp - row * 768u;
  const int* p = adj + (size_t)row * NN + jb * 8;
  int4 x0 = *(const int4*)p;
  int4 x1 = *(const int4*)(p + 4);
  unsigned b = (unsigned)(x0.x > 0) | ((unsigned)(x0.y > 0) << 1) |
               ((unsigned)(x0.z > 0) << 2) | ((unsigned)(x0.w > 0) << 3) |
               ((unsigned)(x1.x > 0) << 4) | ((unsigned)(x1.y > 0) << 5) |
               ((unsigned)(x1.z > 0) << 6) | ((unsigned)(x1.w > 0) << 7);
  packed[(size_t)v * NN * 768 + bp] = (unsigned char)b;
}

// ---------------- GEMM1: hT[v][d][i] = (x @ W_v)^T in f16 ----------------
__global__ __launch_bounds__(256, 2) void gemm1_kernel(
    const half_t* __restrict__ xh, const half_t* __restrict__ WT,
    half_t* __restrict__ hT) {
  int v = blockIdx.y;
  int i0 = blockIdx.x * 64;
  int t = threadIdx.x;
  int lane = t & 63, w = t >> 6;
  int lr = lane & 15, lg = lane >> 4;
  const half_t* Wv = WT + (size_t)v * DD * IN_DIM;
  f32x4 acc[4][4] = {};
  for (int kt = 0; kt < 16; ++kt) {
    int k = kt * 32 + lg * 8;
    f16x8 af[4], bf[4];
#pragma unroll
    for (int mf = 0; mf < 4; ++mf)
      af[mf] = *(const f16x8*)(xh + (size_t)(i0 + mf * 16 + lr) * IN_DIM + k);
#pragma unroll
    for (int nf = 0; nf < 4; ++nf)
      bf[nf] = *(const f16x8*)(Wv + (size_t)(w * 64 + nf * 16 + lr) * IN_DIM + k);
#pragma unroll
    for (int mf = 0; mf < 4; ++mf)
#pragma unroll
      for (int nf = 0; nf < 4; ++nf)
        acc[mf][nf] = mfma16(af[mf], bf[nf], acc[mf][nf]);
  }
  __shared__ half_t tr[4][64 * 64];
  char* trw = (char*)tr[w];
#pragma unroll
  for (int mf = 0; mf < 4; ++mf)
#pragma unroll
    for (int nf = 0; nf < 4; ++nf)
#pragma unroll
      for (int r = 0; r < 4; ++r) {
        int dl = nf * 16 + lr;
        int il = mf * 16 + lg * 4 + r;
        unsigned addr = (unsigned)((dl * 128 + il * 2) ^ ((dl & 7) << 4));
        *(half_t*)(trw + addr) = (half_t)acc[mf][nf][r];
      }
  __syncthreads();
  half_t* hTv = hT + (size_t)v * DD * NN;
#pragma unroll
  for (int c = 0; c < 8; ++c) {
    unsigned addr = (unsigned)((lane * 128 + c * 16) ^ ((lane & 7) << 4));
    f16x8 val = *(const f16x8*)(trw + addr);
    *(f16x8*)(hTv + (size_t)(w * 64 + lane) * NN + i0 + c * 8) = val;
  }
}

// ---------------- e1/e2 scores (pre-scaled by log2(e)) ----------------
__global__ void escore_kernel(const half_t* __restrict__ hT,
    const float* __restrict__ as0, const float* __restrict__ as1, const float* __restrict__ as2,
    const float* __restrict__ ad0, const float* __restrict__ ad1, const float* __restrict__ ad2,
    float* __restrict__ e1, float* __restrict__ e2) {
  int v = blockIdx.y;
  int i = blockIdx.x * 256 + threadIdx.x;
  const float* as = (v == 0) ? as0 : (v == 1) ? as1 : as2;
  const float* ad = (v == 0) ? ad0 : (v == 1) ? ad1 : ad2;
  const half_t* h = hT + (size_t)v * DD * NN;
  float acc1 = 0.f, acc2 = 0.f;
  for (int d = 0; d < DD; ++d) {
    float hv = (float)h[(size_t)d * NN + i];
    acc1 = fmaf(hv, as[d], acc1);
    acc2 = fmaf(hv, ad[d], acc2);
  }
  e1[v * NN + i] = acc1 * LOG2E;
  e2[v * NN + i] = acc2 * LOG2E;
}

// ---------------- e2 max per view ----------------
__global__ void e2max_kernel(const float* __restrict__ e2, float* __restrict__ e2m) {
  int v = blockIdx.x;
  __shared__ float red[256];
  float m = -1e30f;
  for (int i = threadIdx.x; i < NN; i += 256) m = fmaxf(m, e2[v * NN + i]);
  red[threadIdx.x] = m;
  __syncthreads();
  for (int s = 128; s > 0; s >>= 1) {
    if (threadIdx.x < s) red[threadIdx.x] = fmaxf(red[threadIdx.x], red[threadIdx.x + s]);
    __syncthreads();
  }
  if (threadIdx.x == 0) e2m[v] = red[0];
}

// ---------------- fused GAT aggregation (packed adj, j-sliced, dbuf P) ----------------
// grid (96, SPLIT, 3): 64 rows x 2048 j's per block.
__global__ __launch_bounds__(256, 2) void gat_kernel(
    const u64* __restrict__ packed, const half_t* __restrict__ hT,
    const float* __restrict__ e1g, const float* __restrict__ e2g,
    const float* __restrict__ e2maxg, half_t* __restrict__ pacc, float* __restrict__ pl) {
  int v = blockIdx.z, s = blockIdx.y;
  int i0 = blockIdx.x * 64;
  int t = threadIdx.x;
  int lane = t & 63, w = t >> 6;
  int lr = lane & 15, lg = lane >> 4;
  int jq = t & 15, rg = t >> 4;
  __shared__ half_t P_lds[2][64 * 64];
  __shared__ float l_lds[64];
  const half_t* hTv = hT + (size_t)v * DD * NN;
  const float* e2v = e2g + v * NN;
  const int jt0 = s * JTILES;
  // per-row constants (rows il = it*16 + rg)
  float e1r[4], mr[4];
  float e2mL = e2maxg[v];
#pragma unroll
  for (int it = 0; it < 4; ++it) {
    float e1i = e1g[v * NN + i0 + it * 16 + rg];
    e1r[it] = e1i;
    float sm = e1i + e2mL;
    mr[it] = fmaxf(sm, 0.2f * sm);   // lrelu upper bound of row max (scaled by L)
  }
  const u64* pbase = packed + ((size_t)v * NN + i0 + rg) * 96;

  f32x4 acc[4][4] = {};
  float lpart[4] = {0.f, 0.f, 0.f, 0.f};
  f16x8 bA[2][4], bB[2][4];
  u64 awA[4], awB[4];

  auto load_b = [&](f16x8 (&buf)[2][4], int jt) {
    int j0 = jt * 64;
#pragma unroll
    for (int kf = 0; kf < 2; ++kf)
#pragma unroll
      for (int nf = 0; nf < 4; ++nf)
        buf[kf][nf] = *(const f16x8*)(hTv + (size_t)(w * 64 + nf * 16 + lr) * NN +
                                      j0 + kf * 32 + lg * 8);
  };
  auto load_aw = [&](u64 (&awt)[4], int jt) {
#pragma unroll
    for (int it = 0; it < 4; ++it) awt[it] = pbase[(size_t)it * 16 * 96 + jt];
  };
  auto comp_p = [&](const u64 (&awt)[4], int jt, int pb) {
    int j0 = jt * 64;
    float4 e2q = *(const float4*)(e2v + j0 + jq * 4);
    float e2a[4] = {e2q.x, e2q.y, e2q.z, e2q.w};
#pragma unroll
    for (int it = 0; it < 4; ++it) {
      int il = it * 16 + rg;
      unsigned bits = (unsigned)(awt[it] >> (jq * 4)) & 0xFu;
      f16x4 ph;
      float ssum = 0.f;
#pragma unroll
      for (int c = 0; c < 4; ++c) {
        float s1 = e1r[it] + e2a[c];
        float u = fmaxf(s1, 0.2f * s1) - mr[it];
        float p = ((bits >> c) & 1u) ? exp2f(u) : 0.f;
        ssum += p;
        ph[c] = (half_t)p;
      }
      lpart[it] += ssum;
      unsigned addr = (unsigned)((il * 128 + jq * 8) ^ ((il & 7) << 4));
      *(f16x4*)((char*)P_lds[pb] + addr) = ph;
    }
  };
  auto do_mfma = [&](const f16x8 (&buf)[2][4], int pb) {
#pragma unroll
    for (int kf = 0; kf < 2; ++kf)
#pragma unroll
      for (int mf = 0; mf < 4; ++mf) {
        int row = mf * 16 + lr;
        unsigned addr = (unsigned)((row * 128 + kf * 64 + lg * 16) ^ ((row & 7) << 4));
        f16x8 af = *(const f16x8*)((const char*)P_lds[pb] + addr);
#pragma unroll
        for (int nf = 0; nf < 4; ++nf)
          acc[mf][nf] = mfma16(af, buf[kf][nf], acc[mf][nf]);
      }
  };

  // prologue: tile 0
  load_b(bA, jt0);
  load_aw(awA, jt0);
  comp_p(awA, jt0, 0);
  __syncthreads();

  for (int jtt = 0; jtt < JTILES; jtt += 2) {
    int jt = jt0 + jtt;
    // even phase: consume P[0]/bA, produce P[1]
    load_b(bB, jt + 1);
    load_aw(awB, jt + 1);
    do_mfma(bA, 0);
    comp_p(awB, jt + 1, 1);
    __syncthreads();
    // odd phase: consume P[1]/bB, produce P[0]
    if (jtt + 2 < JTILES) {
      load_b(bA, jt + 2);
      load_aw(awA, jt + 2);
    }
    do_mfma(bB, 1);
    if (jtt + 2 < JTILES) comp_p(awA, jt + 2, 0);
    __syncthreads();
  }

  // row partial sums (reduce over jq within 16-lane groups)
#pragma unroll
  for (int it = 0; it < 4; ++it) {
    float ssum = lpart[it];
    ssum += __shfl_xor(ssum, 1); ssum += __shfl_xor(ssum, 2);
    ssum += __shfl_xor(ssum, 4); ssum += __shfl_xor(ssum, 8);
    if (lr == 0) l_lds[it * 16 + rg] = ssum;
  }
  __syncthreads();
  size_t sl = (size_t)v * SPLIT + s;
  if (t < 64) pl[sl * NN + i0 + t] = l_lds[t];
  half_t* pa = pacc + sl * (size_t)NN * DD;
#pragma unroll
  for (int mf = 0; mf < 4; ++mf)
#pragma unroll
    for (int r = 0; r < 4; ++r) {
      int il = mf * 16 + lg * 4 + r;
#pragma unroll
      for (int nf = 0; nf < 4; ++nf)
        pa[(size_t)(i0 + il) * DD + w * 64 + nf * 16 + lr] = (half_t)acc[mf][nf][r];
    }
}

// ---------------- combine slices + normalize ----------------
__global__ __launch_bounds__(256) void combine_kernel(const half_t* __restrict__ pacc,
    const float* __restrict__ pl, half_t* __restrict__ outv) {
  int gid = blockIdx.x * 256 + threadIdx.x;  // 3*6144*32 threads
  int v = gid / (NN * 32);
  int rem = gid - v * (NN * 32);
  int i = rem >> 5, d0 = (rem & 31) * 8;
  float l = pl[((size_t)v * SPLIT + 0) * NN + i] +
            pl[((size_t)v * SPLIT + 1) * NN + i] +
            pl[((size_t)v * SPLIT + 2) * NN + i];
  float rl = (l > 0.f) ? 1.f / l : 0.f;
  f16x8 a0 = *(const f16x8*)(pacc + (((size_t)v * SPLIT + 0) * NN + i) * DD + d0);
  f16x8 a1 = *(const f16x8*)(pacc + (((size_t)v * SPLIT + 1) * NN + i) * DD + d0);
  f16x8 a2 = *(const f16x8*)(pacc + (((size_t)v * SPLIT + 2) * NN + i) * DD + d0);
  f16x8 o;
#pragma unroll
  for (int e = 0; e < 8; ++e)
    o[e] = (half_t)(((float)a0[e] + (float)a1[e] + (float)a2[e]) * rl);
  *(f16x8*)(outv + ((size_t)v * NN + i) * DD + d0) = o;
}

// ---------------- proj + LN + weighted combine ----------------
__global__ __launch_bounds__(256, 2) void proj_kernel(
    const half_t* __restrict__ outv, const half_t* __restrict__ pWT,
    const float* __restrict__ proj_b, const float* __restrict__ ln_g,
    const float* __restrict__ ln_b, const float* __restrict__ alpha,
    float* __restrict__ out) {
  int i0 = blockIdx.x * 64;
  int t = threadIdx.x, lane = t & 63, w = t >> 6;
  int lr = lane & 15, lg = lane >> 4;
  float a0 = alpha[0], a1 = alpha[1], a2 = alpha[2];
  float am = fmaxf(a0, fmaxf(a1, a2));
  float x0 = __expf(a0 - am), x1 = __expf(a1 - am), x2 = __expf(a2 - am);
  float inv = 1.f / (x0 + x1 + x2);
  float wv[3] = {x0 * inv, x1 * inv, x2 * inv};
  f32x4 zacc[8] = {};
  float pb[8], gg[8], bb[8];
#pragma unroll
  for (int nf = 0; nf < 8; ++nf) {
    pb[nf] = proj_b[nf * 16 + lr];
    gg[nf] = ln_g[nf * 16 + lr];
    bb[nf] = ln_b[nf * 16 + lr];
  }
  for (int v = 0; v < 3; ++v) {
    f32x4 yac[8] = {};
    const half_t* ovv = outv + (size_t)v * NN * DD;
    for (int kt = 0; kt < 8; ++kt) {
      int k = kt * 32 + lg * 8;
      f16x8 af = *(const f16x8*)(ovv + (size_t)(i0 + w * 16 + lr) * DD + k);
#pragma unroll
      for (int nf = 0; nf < 8; ++nf) {
        f16x8 bf = *(const f16x8*)(pWT + (size_t)(nf * 16 + lr) * DD + k);
        yac[nf] = mfma16(af, bf, yac[nf]);
      }
    }
#pragma unroll
    for (int r = 0; r < 4; ++r) {
      float ssum = 0.f, q = 0.f;
#pragma unroll
      for (int nf = 0; nf < 8; ++nf) {
        float y = yac[nf][r] + pb[nf];
        yac[nf][r] = y;
        ssum += y; q += y * y;
      }
      ssum += __shfl_xor(ssum, 1); ssum += __shfl_xor(ssum, 2);
      ssum += __shfl_xor(ssum, 4); ssum += __shfl_xor(ssum, 8);
      q += __shfl_xor(q, 1); q += __shfl_xor(q, 2);
      q += __shfl_xor(q, 4); q += __shfl_xor(q, 8);
      float mean = ssum * (1.f / 128.f);
      float var = q * (1.f / 128.f) - mean * mean;
      float rstd = rsqrtf(var + 1e-5f);
      float wvv = wv[v];
#pragma unroll
      for (int nf = 0; nf < 8; ++nf)
        zacc[nf][r] += wvv * (yac[nf][r] - mean) * rstd;
    }
  }
#pragma unroll
  for (int nf = 0; nf < 8; ++nf)
#pragma unroll
    for (int r = 0; r < 4; ++r) {
      int row = i0 + w * 16 + lg * 4 + r;
      float z = zacc[nf][r] * gg[nf] + bb[nf];
      if (!isfinite(z)) z = 0.f;
      out[(size_t)row * OUT_DIM + nf * 16 + lr] = z;
    }
  if (blockIdx.x == 0 && t < 3) out[(size_t)NN * OUT_DIM + t] = wv[t];
}

// ---------------- launch ----------------
extern "C" void kernel_launch(void* const* d_in, const int* in_sizes, int n_in,
                              void* d_out, int out_size, void* d_ws, size_t ws_size,
                              hipStream_t stream) {
  const float* x      = (const float*)d_in[0];
  const int*   adj_cf = (const int*)d_in[1];
  const int*   adj_or = (const int*)d_in[2];
  const int*   adj_pe = (const int*)d_in[3];
  const float* W_cf   = (const float*)d_in[4];
  const float* as_cf  = (const float*)d_in[5];
  const float* ad_cf  = (const float*)d_in[6];
  const float* W_or   = (const float*)d_in[7];
  const float* as_or  = (const float*)d_in[8];
  const float* ad_or  = (const float*)d_in[9];
  const float* W_pe   = (const float*)d_in[10];
  const float* as_pe  = (const float*)d_in[11];
  const float* ad_pe  = (const float*)d_in[12];
  const float* proj_W = (const float*)d_in[13];
  const float* proj_b = (const float*)d_in[14];
  const float* ln_g   = (const float*)d_in[15];
  const float* ln_b   = (const float*)d_in[16];
  const float* alpha  = (const float*)d_in[17];

  char* ws = (char*)d_ws;
  half_t* xh     = (half_t*)(ws + 0);         // 6291456
  half_t* WT     = (half_t*)(ws + 6291456);   // 786432
  half_t* pWT    = (half_t*)(ws + 7077888);   // 65536
  half_t* hT     = (half_t*)(ws + 7143424);   // 9437184
  float*  e1     = (float*)(ws + 16580608);   // 73728
  float*  e2     = (float*)(ws + 16654336);   // 73728
  float*  e2m    = (float*)(ws + 16728064);   // 64 (padded)
  half_t* outv   = (half_t*)(ws + 16728128);  // 9437184
  char*   packed = (char*)(ws + 26165312);    // 3*6144*768 = 14155776
  half_t* pacc   = (half_t*)(ws + 40321088);  // 28311552
  float*  pl     = (float*)(ws + 68632640);   // 221184

  cvt_x_kernel<<<3072, 256, 0, stream>>>(x, xh);
  cvt_w_kernel<<<dim3(512, 4), 256, 0, stream>>>(W_cf, W_or, W_pe, proj_W, WT, pWT);
  gemm1_kernel<<<dim3(96, 3), 256, 0, stream>>>(xh, WT, hT);
  escore_kernel<<<dim3(24, 3), 256, 0, stream>>>(hT, as_cf, as_or, as_pe,
                                                 ad_cf, ad_or, ad_pe, e1, e2);
  e2max_kernel<<<3, 256, 0, stream>>>(e2, e2m);
  pack_kernel<<<dim3(18432, 3), 256, 0, stream>>>(adj_cf, adj_or, adj_pe,
                                                  (unsigned char*)packed);
  gat_kernel<<<dim3(96, SPLIT, 3), 256, 0, stream>>>((const u64*)packed, hT, e1, e2, e2m,
                                                     pacc, pl);
  combine_kernel<<<2304, 256, 0, stream>>>(pacc, pl, outv);
  proj_kernel<<<96, 256, 0, stream>>>(outv, pWT, proj_b, ln_g, ln_b, alpha, (float*)d_out);
}